// Round 2
// baseline (331.922 us; speedup 1.0000x reference)
//
#include <hip/hip_runtime.h>

typedef float v4f __attribute__((ext_vector_type(4)));
typedef float v2f __attribute__((ext_vector_type(2)));

// ---------------- fast device math ----------------
__device__ __forceinline__ float fdiv_fast(float a, float b) {
    return __fdividef(a, b);
}

__device__ __forceinline__ float tanh_fast(float x) {
    // tanh(x) = (e^{2x}-1)/(e^{2x}+1); clamp to avoid inf/inf
    float t = fminf(fmaxf(2.0f * x, -80.0f), 80.0f);
    float e = __expf(t);
    return fdiv_fast(e - 1.0f, e + 1.0f);
}

__device__ __forceinline__ float asinh_pos(float x) {
    // x >= 0 in this problem (current i in [1,3] A)
    return __logf(x + sqrtf(fmaf(x, x, 1.0f)));
}

// physical constants (match reference, f32)
#define RTF       (8.3144621f / 96487.0f)   // R/F
#define VOLS_     2.2e-06f                  // 0.1*VOL
#define VOLB_     1.98e-05f                 // VOL - VOLS
#define INV_TDIFF (1.0f / 7.0e6f)

struct Weights {
    float w0[8], b0[8], w2[32], b2[4], w4[4];
    float b4, wn, bn;
};

__device__ __forceinline__ void compute_row(
    float i, float qm, float ro, v4f s0, v4f s1, const Weights& W,
    float& V, v4f& o0, v4f& o1)
{
    float Tb  = s0.x, Vo  = s0.y, Vsn = s0.z, Vsp = s0.w;
    float qnB = s1.x, qnS = s1.y, qpB = s1.z, qpS = s1.w;

    // ---- getNextState ----
    float qSMax = qm * 1000.0f;               // qMax*QMAX_BASE*VOLS/VOL
    float invq  = fdiv_fast(1.0f, qSMax);

    float xpS = fminf(fmaxf(qpS * invq, 1e-18f), 1.0f);
    float xnS = fminf(fmaxf(qnS * invq, 1e-18f), 1.0f);
    float Jn0 = 1e-18f + 20000.0f * sqrtf((1.0f - xnS) * xnS);
    float Jp0 = 1e-18f + 20000.0f * sqrtf((1.0f - xpS) * xpS);

    float qdotn = (qnB * (1.0f / VOLB_) - qnS * (1.0f / VOLS_)) * INV_TDIFF;
    float qdotp = (qpB * (1.0f / VOLB_) - qpS * (1.0f / VOLS_)) * INV_TDIFF;

    float Jn = i * 5000.0f;                   // i/SN
    float Jp = i * 5000.0f;                   // i/SP
    float VoNom  = i * ro * 10.0f;            // i*Ro*RoBASE
    float coef   = RTF * Tb * 2.0f;           // R*Tb/F/ALPHA
    float VsnNom = coef * asinh_pos(fdiv_fast(Jn, 2.0f * Jn0));
    float VspNom = coef * asinh_pos(fdiv_fast(Jp, 2.0f * Jp0));

    float Vo2  = Vo  + (VoNom  - Vo ) * 0.1f;
    float Vsn2 = Vsn + (VsnNom - Vsn) * (1.0f / 90.0f);
    float Vsp2 = Vsp + (VspNom - Vsp) * (1.0f / 90.0f);
    float qnB2 = qnB - qdotn;
    float qnS2 = qnS + qdotn - i;
    float qpB2 = qpB - qdotp;
    float qpS2 = qpS + i + qdotp;

    // ---- getNextOutput (on XNew) ----
    float xp = qpS2 * invq;   // unclipped, as in reference
    float xn = qnS2 * invq;

    float h1[8];
#pragma unroll
    for (int j = 0; j < 8; j++)
        h1[j] = tanh_fast(fmaf(xp, W.w0[j], W.b0[j]));
    float vep_mlp = W.b4;
#pragma unroll
    for (int k = 0; k < 4; k++) {
        float a = W.b2[k];
#pragma unroll
        for (int j = 0; j < 8; j++)
            a = fmaf(h1[j], W.w2[k * 8 + j], a);
        vep_mlp = fmaf(tanh_fast(a), W.w4[k], vep_mlp);
    }
    float ven_mlp = fmaf(xn, W.wn, W.bn);

    float rp = fminf(fmaxf(fdiv_fast(1.0f - xp, xp), 1e-18f), 1e18f);
    float rn = fminf(fmaxf(fdiv_fast(1.0f - xn, xn), 1e-18f), 1e18f);
    float rtb = RTF * Tb;   // Tb2 == Tb
    float Vep = 4.03f + rtb * __logf(rp) + vep_mlp;
    float Ven = 0.01f + rtb * __logf(rn) + ven_mlp;
    V = Vep - Ven - Vo2 - Vsn2 - Vsp2;

    o0.x = Tb;   o0.y = Vo2;  o0.z = Vsn2; o0.w = Vsp2;
    o1.x = qnB2; o1.y = qnS2; o1.z = qpB2; o1.w = qpS2;
}

// 2 rows per thread: B=4M is even, so every in-range thread has 2 full rows.
__global__ __launch_bounds__(256) void battery_cell_kernel(
    const float* __restrict__ inp,   // [B]
    const float* __restrict__ st,    // [B,8]
    const float* __restrict__ qMaxp, // [B]
    const float* __restrict__ Rop,   // [B]
    const float* __restrict__ Wp0, const float* __restrict__ bp0,
    const float* __restrict__ Wp2, const float* __restrict__ bp2,
    const float* __restrict__ Wp4, const float* __restrict__ bp4,
    const float* __restrict__ Wn,  const float* __restrict__ bn,
    float* __restrict__ outV,        // [B]
    float* __restrict__ outX,        // [B,8]
    int B)
{
    int t = blockIdx.x * blockDim.x + threadIdx.x;
    if (2 * t >= B) return;

    // ---- issue ALL per-row loads up front (nontemporal, streamed) ----
    const v4f* st4 = (const v4f*)st;
    v4f s00 = __builtin_nontemporal_load(st4 + 4 * t + 0);
    v4f s01 = __builtin_nontemporal_load(st4 + 4 * t + 1);
    v4f s10 = __builtin_nontemporal_load(st4 + 4 * t + 2);
    v4f s11 = __builtin_nontemporal_load(st4 + 4 * t + 3);
    v2f iv  = __builtin_nontemporal_load((const v2f*)inp   + t);
    v2f qv  = __builtin_nontemporal_load((const v2f*)qMaxp + t);
    v2f rv  = __builtin_nontemporal_load((const v2f*)Rop   + t);

    // wave-uniform weights (scalar loads)
    Weights W;
#pragma unroll
    for (int j = 0; j < 8; j++) { W.w0[j] = Wp0[j]; W.b0[j] = bp0[j]; }
#pragma unroll
    for (int j = 0; j < 32; j++) W.w2[j] = Wp2[j];
#pragma unroll
    for (int j = 0; j < 4; j++)  { W.b2[j] = bp2[j]; W.w4[j] = Wp4[j]; }
    W.b4 = bp4[0]; W.wn = Wn[0]; W.bn = bn[0];

    float V0, V1;
    v4f o00, o01, o10, o11;
    compute_row(iv.x, qv.x, rv.x, s00, s01, W, V0, o00, o01);
    compute_row(iv.y, qv.y, rv.y, s10, s11, W, V1, o10, o11);

    // ---- stores (nontemporal, streamed) ----
    v2f Vv; Vv.x = V0; Vv.y = V1;
    __builtin_nontemporal_store(Vv, (v2f*)outV + t);
    v4f* ox4 = (v4f*)outX;
    __builtin_nontemporal_store(o00, ox4 + 4 * t + 0);
    __builtin_nontemporal_store(o01, ox4 + 4 * t + 1);
    __builtin_nontemporal_store(o10, ox4 + 4 * t + 2);
    __builtin_nontemporal_store(o11, ox4 + 4 * t + 3);
}

extern "C" void kernel_launch(void* const* d_in, const int* in_sizes, int n_in,
                              void* d_out, int out_size, void* d_ws, size_t ws_size,
                              hipStream_t stream) {
    const float* inp  = (const float*)d_in[0];
    const float* st   = (const float*)d_in[1];
    const float* qMax = (const float*)d_in[2];
    const float* Ro   = (const float*)d_in[3];
    const float* Wp0  = (const float*)d_in[4];
    const float* bp0  = (const float*)d_in[5];
    const float* Wp2  = (const float*)d_in[6];
    const float* bp2  = (const float*)d_in[7];
    const float* Wp4  = (const float*)d_in[8];
    const float* bp4  = (const float*)d_in[9];
    const float* Wn   = (const float*)d_in[10];
    const float* bn   = (const float*)d_in[11];

    int B = in_sizes[0];
    float* outV = (float*)d_out;          // [B]
    float* outX = (float*)d_out + B;      // [B,8]

    int block = 256;
    int threads_needed = (B + 1) / 2;     // 2 rows per thread
    int grid = (threads_needed + block - 1) / block;
    battery_cell_kernel<<<grid, block, 0, stream>>>(
        inp, st, qMax, Ro, Wp0, bp0, Wp2, bp2, Wp4, bp4, Wn, bn,
        outV, outX, B);
}

// Round 3
// 286.859 us; speedup vs baseline: 1.1571x; 1.1571x over previous
//
#include <hip/hip_runtime.h>
#include <math.h>

typedef float v4f __attribute__((ext_vector_type(4)));
typedef float v2f __attribute__((ext_vector_type(2)));

// physical constants (match reference, f32)
#define RTF       (8.3144621f / 96487.0f)   // R/F
#define VOLS_     2.2e-06f                  // 0.1*VOL
#define VOLB_     1.98e-05f                 // VOL - VOLS
#define INV_TDIFF (1.0f / 7.0e6f)

#define LUT_N 4096
// d_ws layout: [0, 16KB): lutJ (float, 1/(2*J0(x)))
//              [16KB, 48KB): lutO (float2: {MLP(x), (R/F)*log(clip((1-x)/x))})

__device__ __forceinline__ float fdiv_fast(float a, float b) {
    return __fdividef(a, b);
}

__device__ __forceinline__ float asinh_pos(float x) {
    // x >= 0 here (current i in [1,3] A)
    return __logf(x + sqrtf(fmaf(x, x, 1.0f)));
}

// ---------------- LUT build kernel (runs every launch; 16 blocks) ----------------
__global__ __launch_bounds__(256) void build_lut_kernel(
    const float* __restrict__ Wp0, const float* __restrict__ bp0,
    const float* __restrict__ Wp2, const float* __restrict__ bp2,
    const float* __restrict__ Wp4, const float* __restrict__ bp4,
    float* __restrict__ lutJ, v2f* __restrict__ lutO)
{
    int idx = blockIdx.x * blockDim.x + threadIdx.x;
    if (idx >= LUT_N) return;
    float x = (float)idx * (1.0f / (float)(LUT_N - 1));   // x in [0,1]

    // 1/(2*J0): J0 = 1e-18 + 20000*sqrt(x*(1-x))   (x here plays the clipped xS role)
    float j0 = 1e-18f + 20000.0f * sqrtf(fmaxf(x * (1.0f - x), 0.0f));
    lutJ[idx] = 1.0f / (2.0f * j0);

    // MLP(x): accurate tanh (runs once per entry; cost irrelevant)
    float h1[8];
#pragma unroll
    for (int j = 0; j < 8; j++)
        h1[j] = tanhf(fmaf(x, Wp0[j], bp0[j]));
    float mlp = bp4[0];
#pragma unroll
    for (int k = 0; k < 4; k++) {
        float a = bp2[k];
#pragma unroll
        for (int j = 0; j < 8; j++)
            a = fmaf(h1[j], Wp2[k * 8 + j], a);
        mlp = fmaf(tanhf(a), Wp4[k], mlp);
    }

    // (R/F) * log(clip((1-x)/x, 1e-18, 1e18))
    float r = fminf(fmaxf((1.0f - x) / fmaxf(x, 1e-30f), 1e-18f), 1e18f);
    float lg = RTF * logf(r);

    v2f o; o.x = mlp; o.y = lg;
    lutO[idx] = o;
}

// ---------------- main kernel: 1 row/thread, plain coalesced loads/stores ----------------
__global__ __launch_bounds__(256) void battery_cell_kernel(
    const float* __restrict__ inp,   // [B]
    const float* __restrict__ st,    // [B,8]
    const float* __restrict__ qMaxp, // [B]
    const float* __restrict__ Rop,   // [B]
    const float* __restrict__ Wn,    // [1,1]
    const float* __restrict__ bn,    // [1]
    const float* __restrict__ lutJ,  // [LUT_N]
    const v2f*   __restrict__ lutO,  // [LUT_N]
    float* __restrict__ outV,        // [B]
    float* __restrict__ outX,        // [B,8]
    int B)
{
    int b = blockIdx.x * blockDim.x + threadIdx.x;
    if (b >= B) return;

    const v4f* st4 = (const v4f*)st;
    v4f s0 = st4[2 * b];
    v4f s1 = st4[2 * b + 1];
    float Tb  = s0.x, Vo  = s0.y, Vsn = s0.z, Vsp = s0.w;
    float qnB = s1.x, qnS = s1.y, qpB = s1.z, qpS = s1.w;
    float i   = inp[b];
    float qm  = qMaxp[b];
    float ro  = Rop[b];
    float wn  = Wn[0], wbn = bn[0];

    // ---- getNextState ----
    float invq = fdiv_fast(1.0f, qm * 1000.0f);   // 1/qSMax

    float xpS = fminf(fmaxf(qpS * invq, 1e-18f), 1.0f);
    float xnS = fminf(fmaxf(qnS * invq, 1e-18f), 1.0f);

    // LUT lerp for 1/(2*J0)
    float tn = xnS * (float)(LUT_N - 1);
    float tp = xpS * (float)(LUT_N - 1);
    int in0 = min((int)tn, LUT_N - 2);
    int ip0 = min((int)tp, LUT_N - 2);
    float fn = tn - (float)in0;
    float fp = tp - (float)ip0;
    float jn_a = lutJ[in0], jn_b = lutJ[in0 + 1];
    float jp_a = lutJ[ip0], jp_b = lutJ[ip0 + 1];
    float inv2Jn = fmaf(fn, jn_b - jn_a, jn_a);
    float inv2Jp = fmaf(fp, jp_b - jp_a, jp_a);

    float qdotn = (qnB * (1.0f / VOLB_) - qnS * (1.0f / VOLS_)) * INV_TDIFF;
    float qdotp = (qpB * (1.0f / VOLB_) - qpS * (1.0f / VOLS_)) * INV_TDIFF;

    float Jn = i * 5000.0f;                 // i/SN (== i/SP)
    float VoNom  = i * ro * 10.0f;
    float coef   = RTF * Tb * 2.0f;         // R*Tb/F/ALPHA
    float VsnNom = coef * asinh_pos(Jn * inv2Jn);
    float VspNom = coef * asinh_pos(Jn * inv2Jp);

    float Vo2  = Vo  + (VoNom  - Vo ) * 0.1f;
    float Vsn2 = Vsn + (VsnNom - Vsn) * (1.0f / 90.0f);
    float Vsp2 = Vsp + (VspNom - Vsp) * (1.0f / 90.0f);
    float qnB2 = qnB - qdotn;
    float qnS2 = qnS + qdotn - i;
    float qpB2 = qpB - qdotp;
    float qpS2 = qpS + i + qdotp;

    // ---- getNextOutput (on XNew) ----
    float xp = qpS2 * invq;
    float xn = qnS2 * invq;

    // LUT lerp: {MLP, (R/F)*log((1-x)/x)} at xp; log channel at xn
    float tpo = fminf(fmaxf(xp, 0.0f), 1.0f) * (float)(LUT_N - 1);
    float tno = fminf(fmaxf(xn, 0.0f), 1.0f) * (float)(LUT_N - 1);
    int ipo = min((int)tpo, LUT_N - 2);
    int ino = min((int)tno, LUT_N - 2);
    float fpo = tpo - (float)ipo;
    float fno = tno - (float)ino;
    v2f oa = lutO[ipo], ob = lutO[ipo + 1];
    v2f na = lutO[ino], nb = lutO[ino + 1];
    float mlp_p = fmaf(fpo, ob.x - oa.x, oa.x);
    float log_p = fmaf(fpo, ob.y - oa.y, oa.y);
    float log_n = fmaf(fno, nb.y - na.y, na.y);

    float Vep = 4.03f + Tb * log_p + mlp_p;
    float Ven = 0.01f + Tb * log_n + fmaf(xn, wn, wbn);
    float V = Vep - Ven - Vo2 - Vsn2 - Vsp2;

    // ---- stores (plain, write-combining via L2) ----
    outV[b] = V;
    v4f o0; o0.x = Tb;   o0.y = Vo2;  o0.z = Vsn2; o0.w = Vsp2;
    v4f o1; o1.x = qnB2; o1.y = qnS2; o1.z = qpB2; o1.w = qpS2;
    v4f* ox4 = (v4f*)outX;
    ox4[2 * b]     = o0;
    ox4[2 * b + 1] = o1;
}

extern "C" void kernel_launch(void* const* d_in, const int* in_sizes, int n_in,
                              void* d_out, int out_size, void* d_ws, size_t ws_size,
                              hipStream_t stream) {
    const float* inp  = (const float*)d_in[0];
    const float* st   = (const float*)d_in[1];
    const float* qMax = (const float*)d_in[2];
    const float* Ro   = (const float*)d_in[3];
    const float* Wp0  = (const float*)d_in[4];
    const float* bp0  = (const float*)d_in[5];
    const float* Wp2  = (const float*)d_in[6];
    const float* bp2  = (const float*)d_in[7];
    const float* Wp4  = (const float*)d_in[8];
    const float* bp4  = (const float*)d_in[9];
    const float* Wn   = (const float*)d_in[10];
    const float* bn   = (const float*)d_in[11];

    int B = in_sizes[0];
    float* outV = (float*)d_out;
    float* outX = (float*)d_out + B;

    float* lutJ = (float*)d_ws;                        // 16 KB
    v2f*   lutO = (v2f*)((char*)d_ws + LUT_N * 4);     // 32 KB

    build_lut_kernel<<<LUT_N / 256, 256, 0, stream>>>(
        Wp0, bp0, Wp2, bp2, Wp4, bp4, lutJ, lutO);

    int block = 256;
    int grid = (B + block - 1) / block;
    battery_cell_kernel<<<grid, block, 0, stream>>>(
        inp, st, qMax, Ro, Wn, bn, lutJ, lutO, outV, outX, B);
}